// Round 6
// baseline (230.901 us; speedup 1.0000x reference)
//
#include <hip/hip_runtime.h>
#include <hip/hip_bf16.h>

#define IMG   224
#define HO    112
#define WO_   112
#define EMBED 192
#define BATCH 32

// Branch-free exact-GELU: 0.5*a*(1+erf(a/sqrt(2))), erf via A&S 7.1.26
// (|err| <= 1.5e-7, no branches, ~15 VALU ops incl. v_rcp/v_exp2).
__device__ __forceinline__ float fast_gelu(float a) {
    float x  = a * 0.70710678118654752f;
    float ax = fabsf(x);
    float t  = __builtin_amdgcn_rcpf(fmaf(0.3275911f, ax, 1.0f));
    float p  = fmaf(t, 1.061405429f, -1.453152027f);
    p = fmaf(t, p, 1.421413741f);
    p = fmaf(t, p, -0.284496736f);
    p = fmaf(t, p, 0.254829592f);
    p = p * t;
    float ex  = __builtin_amdgcn_exp2f(x * x * -1.44269504088896341f);
    float er  = fmaf(-p, ex, 1.0f);          // erf(|x|)
    er = copysignf(er, x);
    return 0.5f * a * (1.0f + er);
}

// One thread per (b, ho, wo): conv3x3-s2 (192 ch) -> GELU -> 2-dim projection.
// Channels processed in pairs: two independent FMA chains hide 4-cyc latency.
__global__ __launch_bounds__(256)
void offsets_kernel(const float* __restrict__ x,
                    const float* __restrict__ conv_w,
                    const float* __restrict__ conv_b,
                    const float* __restrict__ off_w,
                    float* __restrict__ off_out) {
    int pos = blockIdx.x * 256 + threadIdx.x;   // grid covers exactly B*HO*WO
    int wo = pos % WO_;
    int t  = pos / WO_;
    int ho = t % HO;
    int b  = t / HO;

    float xv[27];
    int iy0 = 2 * ho - 1, ix0 = 2 * wo - 1;
#pragma unroll
    for (int c = 0; c < 3; ++c) {
        const float* xc = x + ((size_t)(b * 3 + c)) * IMG * IMG;
#pragma unroll
        for (int ky = 0; ky < 3; ++ky) {
            int iy = iy0 + ky;
#pragma unroll
            for (int kx = 0; kx < 3; ++kx) {
                int ix = ix0 + kx;
                float v = 0.0f;
                if (iy >= 0 && iy < IMG && ix >= 0 && ix < IMG)
                    v = xc[iy * IMG + ix];
                xv[c * 9 + ky * 3 + kx] = v;
            }
        }
    }

    float offx = 0.0f, offy = 0.0f;
    for (int e = 0; e < EMBED; e += 2) {
        const float* w0 = conv_w + e * 27;       // wave-uniform -> scalar loads
        const float* w1 = w0 + 27;
        float acc0 = conv_b[e];
        float acc1 = conv_b[e + 1];
#pragma unroll
        for (int i = 0; i < 27; ++i) {
            acc0 = fmaf(w0[i], xv[i], acc0);
            acc1 = fmaf(w1[i], xv[i], acc1);
        }
        float g0 = fast_gelu(acc0);
        float g1 = fast_gelu(acc1);
        offx = fmaf(g0, off_w[e],             offx);
        offy = fmaf(g0, off_w[EMBED + e],     offy);
        offx = fmaf(g1, off_w[e + 1],         offx);
        offy = fmaf(g1, off_w[EMBED + e + 1], offy);
    }
    off_out[pos * 2 + 0] = offx * 2.0f;   // * PATCH_SIZE
    off_out[pos * 2 + 1] = offy * 2.0f;
}

// One thread per output pixel: out[b][c][ho*4+py][wo*4+px], fp32 out.
__global__ __launch_bounds__(256)
void resample_kernel(const float* __restrict__ x,
                     const float* __restrict__ off,
                     float* __restrict__ out) {
    int tid = blockIdx.x * 256 + threadIdx.x;
    int ox = tid % 448;
    int t  = tid / 448;
    int oy = t % 448;
    t /= 448;
    int c = t % 3;
    int b = t / 3;

    int ho = oy >> 2, py = oy & 3;
    int wo = ox >> 2, px = ox & 3;
    int pos = (b * HO + ho) * WO_ + wo;
    float ofx = off[pos * 2 + 0];
    float ofy = off[pos * 2 + 1];

    float ys = (ho + 0.5f) * 2.0f + ofy + ((py + 0.5f) * 0.5f - 1.0f);
    float xs = (wo + 0.5f) * 2.0f + ofx + ((px + 0.5f) * 0.5f - 1.0f);

    float y0f = floorf(ys), x0f = floorf(xs);
    float wy = ys - y0f, wx = xs - x0f;
    int y0 = (int)y0f; y0 = min(max(y0, 0), IMG - 1);
    int x0 = (int)x0f; x0 = min(max(x0, 0), IMG - 1);
    int y1 = min(y0 + 1, IMG - 1);
    int x1 = min(x0 + 1, IMG - 1);

    const float* xc = x + ((size_t)(b * 3 + c)) * IMG * IMG;
    float v00 = xc[y0 * IMG + x0];
    float v01 = xc[y0 * IMG + x1];
    float v10 = xc[y1 * IMG + x0];
    float v11 = xc[y1 * IMG + x1];

    float rv = v00 * (1.0f - wy) * (1.0f - wx) + v01 * (1.0f - wy) * wx
             + v10 * wy * (1.0f - wx)          + v11 * wy * wx;
    out[tid] = rv;
}

extern "C" void kernel_launch(void* const* d_in, const int* in_sizes, int n_in,
                              void* d_out, int out_size, void* d_ws, size_t ws_size,
                              hipStream_t stream) {
    const float* x      = (const float*)d_in[0];
    const float* conv_w = (const float*)d_in[1];
    const float* conv_b = (const float*)d_in[2];
    const float* off_w  = (const float*)d_in[3];
    float* off_buf = (float*)d_ws;            // 401408*2 floats = 3.2 MB
    float* out = (float*)d_out;

    offsets_kernel<<<BATCH * HO * WO_ / 256, 256, 0, stream>>>(
        x, conv_w, conv_b, off_w, off_buf);   // 1568 blocks

    resample_kernel<<<BATCH * 3 * 448 * 448 / 256, 256, 0, stream>>>(
        x, off_buf, out);                     // 75264 blocks
}

// Round 7
// 198.804 us; speedup vs baseline: 1.1615x; 1.1615x over previous
//
#include <hip/hip_runtime.h>
#include <hip/hip_bf16.h>

#define IMG   224
#define HO    112
#define WO_   112
#define EMBED 192
#define BATCH 32
#define NPOS  (BATCH * HO * WO_)   // 401408
#define TPW   8                     // position-tiles (of 16) per wave

typedef __attribute__((ext_vector_type(8))) short short8;
typedef __attribute__((ext_vector_type(4))) float float4v;

__device__ __forceinline__ short f2bf(float f) {      // fp32 -> bf16 (RNE)
    unsigned u = __builtin_bit_cast(unsigned, f);
    u += 0x7FFFu + ((u >> 16) & 1u);
    return (short)(u >> 16);
}

// Branch-free exact-GELU via A&S 7.1.26 erf (|err|<=1.5e-7). Validated r6:
// absmax identical to ocml erff path (0.0078125).
__device__ __forceinline__ float fast_gelu(float a) {
    float x  = a * 0.70710678118654752f;
    float ax = fabsf(x);
    float t  = __builtin_amdgcn_rcpf(fmaf(0.3275911f, ax, 1.0f));
    float p  = fmaf(t, 1.061405429f, -1.453152027f);
    p = fmaf(t, p, 1.421413741f);
    p = fmaf(t, p, -0.284496736f);
    p = fmaf(t, p, 0.254829592f);
    p = p * t;
    float ex = __builtin_amdgcn_exp2f(x * x * -1.44269504088896341f);
    float er = copysignf(fmaf(-p, ex, 1.0f), x);
    return 0.5f * a * (1.0f + er);
}

// MFMA conv: feat[pos][ch] = patches[pos][k27] @ conv_w[ch][k27]^T (+bias via
// k=27 slot, input 1.0). One wave: 16 pos x 192 ch = 12 MFMAs per tile, 8
// tiles per wave. GELU + off_w projection + shfl-reduce over channel lanes.
__global__ __launch_bounds__(256)
void offsets_kernel(const float* __restrict__ x,
                    const float* __restrict__ conv_w,
                    const float* __restrict__ conv_b,
                    const float* __restrict__ off_w,
                    float* __restrict__ off_out) {
    int lane = threadIdx.x & 63;
    int wave = (blockIdx.x * 256 + threadIdx.x) >> 6;   // 0..3135
    int col  = lane & 15;
    int quad = lane >> 4;

    // ---- Preload B frags (weights, all waves identical; L2-hot) ----
    short8 bfrag[12];
#pragma unroll
    for (int nt = 0; nt < 12; ++nt) {
        int ch = nt * 16 + col;
#pragma unroll
        for (int j = 0; j < 8; ++j) {
            int k = quad * 8 + j;
            float v = (k < 27) ? conv_w[ch * 27 + k]
                               : ((k == 27) ? conv_b[ch] : 0.0f);
            bfrag[nt][j] = f2bf(v);
        }
    }
    float owx[12], owy[12];
#pragma unroll
    for (int nt = 0; nt < 12; ++nt) {
        owx[nt] = off_w[nt * 16 + col];
        owy[nt] = off_w[EMBED + nt * 16 + col];
    }

    for (int it = 0; it < TPW; ++it) {
        int pos0 = wave * (16 * TPW) + it * 16;
        // ---- A-frag gather: this lane's position = pos0 + col ----
        int pos = pos0 + col;
        int wo = pos % WO_;
        int t2 = pos / WO_;
        int ho = t2 % HO;
        int b  = t2 / HO;
        int iy0 = 2 * ho - 1, ix0 = 2 * wo - 1;
        const float* xb = x + (size_t)b * 3 * IMG * IMG;

        short8 afrag;
#pragma unroll
        for (int j = 0; j < 8; ++j) {
            int k = quad * 8 + j;
            float v;
            if (k < 27) {
                int c  = k / 9;
                int r9 = k % 9;
                int iy = iy0 + r9 / 3;
                int ix = ix0 + r9 % 3;
                v = (iy >= 0 && iy < IMG && ix >= 0 && ix < IMG)
                        ? xb[(size_t)c * IMG * IMG + iy * IMG + ix] : 0.0f;
            } else {
                v = (k == 27) ? 1.0f : 0.0f;   // bias slot
            }
            afrag[j] = f2bf(v);
        }

        // ---- 12 MFMAs + GELU + projection ----
        float ox[4] = {0, 0, 0, 0}, oy[4] = {0, 0, 0, 0};
#pragma unroll
        for (int nt = 0; nt < 12; ++nt) {
            float4v c = {0.0f, 0.0f, 0.0f, 0.0f};
            c = __builtin_amdgcn_mfma_f32_16x16x32_bf16(afrag, bfrag[nt], c, 0, 0, 0);
            // c[r]: feat[pos = pos0 + quad*4 + r][ch = nt*16 + col]
#pragma unroll
            for (int r = 0; r < 4; ++r) {
                float g = fast_gelu(c[r]);
                ox[r] = fmaf(g, owx[nt], ox[r]);
                oy[r] = fmaf(g, owy[nt], oy[r]);
            }
        }

        // ---- reduce over the 16 channel-lanes (col) ----
#pragma unroll
        for (int d = 1; d < 16; d <<= 1) {
#pragma unroll
            for (int r = 0; r < 4; ++r) {
                ox[r] += __shfl_xor(ox[r], d, 64);
                oy[r] += __shfl_xor(oy[r], d, 64);
            }
        }
        if (col == 0) {
            int p = pos0 + quad * 4;
#pragma unroll
            for (int r = 0; r < 4; ++r) {
                float2 v = make_float2(ox[r] * 2.0f, oy[r] * 2.0f); // * PATCH_SIZE
                ((float2*)off_out)[p + r] = v;
            }
        }
    }
}

// 4 output px per thread (one patch cell row): shared ys/y0/y1/off, float4 store.
__global__ __launch_bounds__(256)
void resample_kernel(const float* __restrict__ x,
                     const float* __restrict__ off,
                     float* __restrict__ out) {
    int gid = blockIdx.x * 256 + threadIdx.x;       // 4.8M threads
    int wo = gid % WO_;
    int t  = gid / WO_;
    int oy = t % 448;
    int bc = t / 448;                               // b*3 + c
    int c  = bc % 3;
    int b  = bc / 3;

    int ho = oy >> 2, py = oy & 3;
    int pos = (b * HO + ho) * WO_ + wo;
    float2 ofs = ((const float2*)off)[pos];

    float ys = (ho + 0.5f) * 2.0f + ofs.y + ((py + 0.5f) * 0.5f - 1.0f);
    float y0f = floorf(ys);
    float wy = ys - y0f;
    int y0 = (int)y0f; y0 = min(max(y0, 0), IMG - 1);
    int y1 = min(y0 + 1, IMG - 1);

    const float* xc = x + ((size_t)(b * 3 + c)) * IMG * IMG;
    const float* row0 = xc + y0 * IMG;
    const float* row1 = xc + y1 * IMG;

    float xs0 = (wo + 0.5f) * 2.0f + ofs.x - 0.75f; // px=0; step 0.5
    float4v res;
#pragma unroll
    for (int p = 0; p < 4; ++p) {
        float xs = xs0 + 0.5f * p;
        float x0f = floorf(xs);
        float wx = xs - x0f;
        int x0 = (int)x0f; x0 = min(max(x0, 0), IMG - 1);
        int x1 = min(x0 + 1, IMG - 1);
        float v00 = row0[x0], v01 = row0[x1];
        float v10 = row1[x0], v11 = row1[x1];
        float top = v00 + (v01 - v00) * wx;   // == v00*(1-wx)+v01*wx exactly? keep explicit form
        top = v00 * (1.0f - wx) + v01 * wx;
        float bot = v10 * (1.0f - wx) + v11 * wx;
        res[p] = top * (1.0f - wy) + bot * wy;
    }
    ((float4v*)out)[gid] = res;
}

extern "C" void kernel_launch(void* const* d_in, const int* in_sizes, int n_in,
                              void* d_out, int out_size, void* d_ws, size_t ws_size,
                              hipStream_t stream) {
    const float* x      = (const float*)d_in[0];
    const float* conv_w = (const float*)d_in[1];
    const float* conv_b = (const float*)d_in[2];
    const float* off_w  = (const float*)d_in[3];
    float* off_buf = (float*)d_ws;             // 401408*2 floats = 3.2 MB
    float* out = (float*)d_out;

    // 3136 waves * 128 positions = 401408; 784 blocks (~3/CU)
    offsets_kernel<<<NPOS / (128 * 4), 256, 0, stream>>>(
        x, conv_w, conv_b, off_w, off_buf);

    // 19267584 px / 4 per thread / 256 = 18816 blocks
    resample_kernel<<<BATCH * 3 * 448 * WO_ / 256, 256, 0, stream>>>(
        x, off_buf, out);
}

// Round 8
// 169.633 us; speedup vs baseline: 1.3612x; 1.1720x over previous
//
#include <hip/hip_runtime.h>
#include <hip/hip_bf16.h>

#define IMG   224
#define HO    112
#define WO_   112
#define EMBED 192
#define BATCH 32
#define NPOS  (BATCH * HO * WO_)   // 401408
#define TPW   4                     // 16-pos tiles per wave

typedef __attribute__((ext_vector_type(8))) short short8;
typedef __attribute__((ext_vector_type(4))) float float4v;

__device__ __forceinline__ short f2bf(float f) {      // fp32 -> bf16 (RNE)
    unsigned u = __builtin_bit_cast(unsigned, f);
    u += 0x7FFFu + ((u >> 16) & 1u);
    return (short)(u >> 16);
}

// Branch-free exact-GELU via A&S 7.1.26 erf (|err|<=1.5e-7).
__device__ __forceinline__ float fast_gelu(float a) {
    float x  = a * 0.70710678118654752f;
    float ax = fabsf(x);
    float t  = __builtin_amdgcn_rcpf(fmaf(0.3275911f, ax, 1.0f));
    float p  = fmaf(t, 1.061405429f, -1.453152027f);
    p = fmaf(t, p, 1.421413741f);
    p = fmaf(t, p, -0.284496736f);
    p = fmaf(t, p, 0.254829592f);
    p = p * t;
    float ex = __builtin_amdgcn_exp2f(x * x * -1.44269504088896341f);
    float er = copysignf(fmaf(-p, ex, 1.0f), x);
    return 0.5f * a * (1.0f + er);
}

// Fused: MFMA conv -> GELU -> projection -> (LDS) -> deformable resample.
// Block = 4 waves; wave handles 4 tiles of 16 positions (block = 256 pos).
// Phase 2: each wave resamples its own 64 patches (48 px each).
__global__ __launch_bounds__(256)
void fused_kernel(const float* __restrict__ x,
                  const float* __restrict__ conv_w,
                  const float* __restrict__ conv_b,
                  const float* __restrict__ off_w,
                  float* __restrict__ out) {
    __shared__ float s_off[4][TPW][16][2];   // [wave][tile][patch][xy] = 2 KB

    int lane = threadIdx.x & 63;
    int wv   = threadIdx.x >> 6;
    int gw   = blockIdx.x * 4 + wv;          // global wave, 0..6271
    int base = gw * (16 * TPW);              // first position of this wave
    int col  = lane & 15;
    int quad = lane >> 4;

    // ---- B frags (conv weights + bias slot k=27), off_w per-lane ----
    short8 bfrag[12];
#pragma unroll
    for (int nt = 0; nt < 12; ++nt) {
        int ch = nt * 16 + col;
#pragma unroll
        for (int j = 0; j < 8; ++j) {
            int k = quad * 8 + j;
            float v = (k < 27) ? conv_w[ch * 27 + k]
                               : ((k == 27) ? conv_b[ch] : 0.0f);
            bfrag[nt][j] = f2bf(v);
        }
    }
    float owx[12], owy[12];
#pragma unroll
    for (int nt = 0; nt < 12; ++nt) {
        owx[nt] = off_w[nt * 16 + col];
        owy[nt] = off_w[EMBED + nt * 16 + col];
    }

    // ---- Phase 1: conv + GELU + projection for 4 tiles ----
    for (int it = 0; it < TPW; ++it) {
        int pos = base + it * 16 + col;
        int wo = pos % WO_;
        int t2 = pos / WO_;
        int ho = t2 % HO;
        int b  = t2 / HO;
        int iy0 = 2 * ho - 1, ix0 = 2 * wo - 1;
        const float* xb = x + (size_t)b * 3 * IMG * IMG;

        short8 afrag;
#pragma unroll
        for (int j = 0; j < 8; ++j) {
            int k = quad * 8 + j;
            float v;
            if (k < 27) {
                int c  = k / 9;
                int r9 = k % 9;
                int iy = iy0 + r9 / 3;
                int ix = ix0 + r9 % 3;
                v = (iy >= 0 && iy < IMG && ix >= 0 && ix < IMG)
                        ? xb[(size_t)c * IMG * IMG + iy * IMG + ix] : 0.0f;
            } else {
                v = (k == 27) ? 1.0f : 0.0f;   // bias slot
            }
            afrag[j] = f2bf(v);
        }

        float ox[4] = {0, 0, 0, 0}, oy[4] = {0, 0, 0, 0};
#pragma unroll
        for (int nt = 0; nt < 12; ++nt) {
            float4v c = {0.0f, 0.0f, 0.0f, 0.0f};
            c = __builtin_amdgcn_mfma_f32_16x16x32_bf16(afrag, bfrag[nt], c, 0, 0, 0);
            // c[r] = feat[base + it*16 + quad*4 + r][nt*16 + col]
#pragma unroll
            for (int r = 0; r < 4; ++r) {
                float g = fast_gelu(c[r]);
                ox[r] = fmaf(g, owx[nt], ox[r]);
                oy[r] = fmaf(g, owy[nt], oy[r]);
            }
        }
#pragma unroll
        for (int d = 1; d < 16; d <<= 1) {
#pragma unroll
            for (int r = 0; r < 4; ++r) {
                ox[r] += __shfl_xor(ox[r], d, 64);
                oy[r] += __shfl_xor(oy[r], d, 64);
            }
        }
        if (col == 0) {
#pragma unroll
            for (int r = 0; r < 4; ++r) {
                s_off[wv][it][quad * 4 + r][0] = ox[r] * 2.0f;  // * PATCH_SIZE
                s_off[wv][it][quad * 4 + r][1] = oy[r] * 2.0f;
            }
        }
    }
    __syncthreads();   // cheap; guarantees LDS visibility

    // ---- Phase 2: resample 64 patches/wave, 48 px each ----
    // lane -> patch_local = lane>>2 (16 patches), px = lane&3; iter i -> (c,py)
    int patch_local = lane >> 2;
    int px = lane & 3;
    for (int it = 0; it < TPW; ++it) {
        int pos = base + it * 16 + patch_local;
        int wo = pos % WO_;
        int t2 = pos / WO_;
        int ho = t2 % HO;
        int b  = t2 / HO;

        float ofx = s_off[wv][it][patch_local][0];
        float ofy = s_off[wv][it][patch_local][1];

        float xs = (wo + 0.5f) * 2.0f + ofx + ((px + 0.5f) * 0.5f - 1.0f);
        float x0f = floorf(xs);
        float wx = xs - x0f;
        int x0 = (int)x0f; x0 = min(max(x0, 0), IMG - 1);
        int x1 = min(x0 + 1, IMG - 1);

        const float* xb = x + (size_t)b * 3 * IMG * IMG;
        size_t obase = ((size_t)b * 3) * 448 * 448;

#pragma unroll
        for (int i = 0; i < 12; ++i) {
            int c  = i >> 2;
            int py = i & 3;
            float ys = (ho + 0.5f) * 2.0f + ofy + ((py + 0.5f) * 0.5f - 1.0f);
            float y0f = floorf(ys);
            float wy = ys - y0f;
            int y0 = (int)y0f; y0 = min(max(y0, 0), IMG - 1);
            int y1 = min(y0 + 1, IMG - 1);

            const float* xc = xb + (size_t)c * IMG * IMG;
            const float* row0 = xc + y0 * IMG;
            const float* row1 = xc + y1 * IMG;
            float v00 = row0[x0], v01 = row0[x1];
            float v10 = row1[x0], v11 = row1[x1];

            float top = v00 * (1.0f - wx) + v01 * wx;
            float bot = v10 * (1.0f - wx) + v11 * wx;
            float rv  = top * (1.0f - wy) + bot * wy;

            int oy_ = ho * 4 + py;
            int ox_ = wo * 4 + px;
            out[obase + ((size_t)c * 448 + oy_) * 448 + ox_] = rv;
        }
    }
}

extern "C" void kernel_launch(void* const* d_in, const int* in_sizes, int n_in,
                              void* d_out, int out_size, void* d_ws, size_t ws_size,
                              hipStream_t stream) {
    const float* x      = (const float*)d_in[0];
    const float* conv_w = (const float*)d_in[1];
    const float* conv_b = (const float*)d_in[2];
    const float* off_w  = (const float*)d_in[3];
    float* out = (float*)d_out;

    // 1568 blocks (~6 per CU), 256 pos per block: 1568*256 = 401408 = NPOS
    fused_kernel<<<NPOS / 256, 256, 0, stream>>>(x, conv_w, conv_b, off_w, out);
}

// Round 9
// 152.117 us; speedup vs baseline: 1.5179x; 1.1151x over previous
//
#include <hip/hip_runtime.h>
#include <hip/hip_bf16.h>

#define IMG   224
#define HO    112
#define WO_   112
#define EMBED 192
#define BATCH 32
#define NPOS  (BATCH * HO * WO_)   // 401408
#define TPW   4                     // 16-pos tiles per wave

typedef __attribute__((ext_vector_type(8))) short short8;
typedef __attribute__((ext_vector_type(4))) float float4v;

__device__ __forceinline__ short f2bf(float f) {      // fp32 -> bf16 (RNE)
    unsigned u = __builtin_bit_cast(unsigned, f);
    u += 0x7FFFu + ((u >> 16) & 1u);
    return (short)(u >> 16);
}

// Sigmoid-GELU: x*sigmoid(1.702x). |err vs exact| <= 0.008 at |x|<=1.5;
// weighted by off_w (sigma 0.02) the offset error is ~4e-4 px — invisible
// next to bf16-conv quantization (absmax 0.0156 vs threshold 0.0759).
__device__ __forceinline__ float fast_gelu(float a) {
    float e = __builtin_amdgcn_exp2f(a * -2.45546507f);  // exp(-1.702a)
    return a * __builtin_amdgcn_rcpf(1.0f + e);
}

__device__ __forceinline__ short8 gather_afrag(const float* __restrict__ x,
                                               int pos, int quad) {
    int wo = pos % WO_;
    int t2 = pos / WO_;
    int ho = t2 % HO;
    int b  = t2 / HO;
    int iy0 = 2 * ho - 1, ix0 = 2 * wo - 1;
    const float* xb = x + (size_t)b * 3 * IMG * IMG;
    short8 a;
#pragma unroll
    for (int j = 0; j < 8; ++j) {
        int k = quad * 8 + j;
        float v;
        if (k < 27) {
            int c  = k / 9;
            int r9 = k % 9;
            int iy = iy0 + r9 / 3;
            int ix = ix0 + r9 % 3;
            v = (iy >= 0 && iy < IMG && ix >= 0 && ix < IMG)
                    ? xb[(size_t)c * IMG * IMG + iy * IMG + ix] : 0.0f;
        } else {
            v = (k == 27) ? 1.0f : 0.0f;   // bias slot
        }
        a[j] = f2bf(v);
    }
    return a;
}

// Fused: MFMA conv -> GELU -> projection -> (LDS) -> deformable resample.
// Block = 4 waves; wave handles TPW=4 tiles of 16 positions.
__global__ __launch_bounds__(256)
void fused_kernel(const float* __restrict__ x,
                  const float* __restrict__ conv_w,
                  const float* __restrict__ conv_b,
                  const float* __restrict__ off_w,
                  float* __restrict__ out) {
    __shared__ float s_off[4][TPW][16][2];   // 2 KB

    int lane = threadIdx.x & 63;
    int wv   = threadIdx.x >> 6;
    int gw   = blockIdx.x * 4 + wv;
    int base = gw * (16 * TPW);
    int col  = lane & 15;
    int quad = lane >> 4;

    // ---- B frags (conv weights + bias slot k=27); off_w pre-scaled x2 ----
    short8 bfrag[12];
#pragma unroll
    for (int nt = 0; nt < 12; ++nt) {
        int ch = nt * 16 + col;
#pragma unroll
        for (int j = 0; j < 8; ++j) {
            int k = quad * 8 + j;
            float v = (k < 27) ? conv_w[ch * 27 + k]
                               : ((k == 27) ? conv_b[ch] : 0.0f);
            bfrag[nt][j] = f2bf(v);
        }
    }
    float owx[12], owy[12];
#pragma unroll
    for (int nt = 0; nt < 12; ++nt) {
        owx[nt] = off_w[nt * 16 + col] * 2.0f;            // * PATCH_SIZE
        owy[nt] = off_w[EMBED + nt * 16 + col] * 2.0f;
    }

    // ---- Phase 1, software-pipelined across tiles ----
    short8 afrag = gather_afrag(x, base + col, quad);
    for (int it = 0; it < TPW; ++it) {
        short8 nxt;
        if (it + 1 < TPW) nxt = gather_afrag(x, base + (it + 1) * 16 + col, quad);

        float ox[4] = {0, 0, 0, 0}, oy[4] = {0, 0, 0, 0};
#pragma unroll
        for (int nt = 0; nt < 12; ++nt) {
            float4v c = {0.0f, 0.0f, 0.0f, 0.0f};
            c = __builtin_amdgcn_mfma_f32_16x16x32_bf16(afrag, bfrag[nt], c, 0, 0, 0);
#pragma unroll
            for (int r = 0; r < 4; ++r) {
                float g = fast_gelu(c[r]);
                ox[r] = fmaf(g, owx[nt], ox[r]);
                oy[r] = fmaf(g, owy[nt], oy[r]);
            }
        }
#pragma unroll
        for (int d = 1; d < 16; d <<= 1) {
#pragma unroll
            for (int r = 0; r < 4; ++r) {
                ox[r] += __shfl_xor(ox[r], d, 64);
                oy[r] += __shfl_xor(oy[r], d, 64);
            }
        }
        if (col == 0) {
#pragma unroll
            for (int r = 0; r < 4; ++r) {
                s_off[wv][it][quad * 4 + r][0] = ox[r];
                s_off[wv][it][quad * 4 + r][1] = oy[r];
            }
        }
        afrag = nxt;
    }
    __syncthreads();

    // ---- Phase 2: resample 64 patches/wave, 48 px each ----
    int patch_local = lane >> 2;
    int px = lane & 3;
    for (int it = 0; it < TPW; ++it) {
        int pos = base + it * 16 + patch_local;
        int wo = pos % WO_;
        int t2 = pos / WO_;
        int ho = t2 % HO;
        int b  = t2 / HO;

        float ofx = s_off[wv][it][patch_local][0];
        float ofy = s_off[wv][it][patch_local][1];

        float xs = (wo + 0.5f) * 2.0f + ofx + ((px + 0.5f) * 0.5f - 1.0f);
        float x0f = floorf(xs);
        float wx = xs - x0f;
        int x0 = (int)x0f; x0 = min(max(x0, 0), IMG - 1);
        int x1 = min(x0 + 1, IMG - 1);
        float wx1 = 1.0f - wx;

        const float* xb = x + (size_t)b * 3 * IMG * IMG;
        size_t obase = ((size_t)b * 3) * 448 * 448;
        int ox_ = wo * 4 + px;

#pragma unroll
        for (int py = 0; py < 4; ++py) {
            // y math depends on py only — shared across the 3 channels
            float ys = (ho + 0.5f) * 2.0f + ofy + ((py + 0.5f) * 0.5f - 1.0f);
            float y0f = floorf(ys);
            float wy = ys - y0f;
            int y0 = (int)y0f; y0 = min(max(y0, 0), IMG - 1);
            int y1 = min(y0 + 1, IMG - 1);
            float wy1 = 1.0f - wy;
            int oy_ = ho * 4 + py;

#pragma unroll
            for (int c = 0; c < 3; ++c) {
                const float* xc = xb + (size_t)c * IMG * IMG;
                const float* row0 = xc + y0 * IMG;
                const float* row1 = xc + y1 * IMG;
                float v00 = row0[x0], v01 = row0[x1];
                float v10 = row1[x0], v11 = row1[x1];
                float top = v00 * wx1 + v01 * wx;
                float bot = v10 * wx1 + v11 * wx;
                out[obase + ((size_t)c * 448 + oy_) * 448 + ox_] =
                    top * wy1 + bot * wy;
            }
        }
    }
}

extern "C" void kernel_launch(void* const* d_in, const int* in_sizes, int n_in,
                              void* d_out, int out_size, void* d_ws, size_t ws_size,
                              hipStream_t stream) {
    const float* x      = (const float*)d_in[0];
    const float* conv_w = (const float*)d_in[1];
    const float* conv_b = (const float*)d_in[2];
    const float* off_w  = (const float*)d_in[3];
    float* out = (float*)d_out;

    // 1568 blocks, 256 positions each
    fused_kernel<<<NPOS / 256, 256, 0, stream>>>(x, conv_w, conv_b, off_w, out);
}